// Round 2
// baseline (77.647 us; speedup 1.0000x reference)
//
#include <hip/hip_runtime.h>

// ws layout (floats/ints, 32 B): [0]=loss_sum f32, [1]=trivial_sum f32,
// [2]=n_pos i32, [3]=n_neg i32, [4]=ticket i32
//
// Single fused kernel:
//  - 2D grid: x = i-tile (512 i per block: 256 threads x 2), y = j-tile (256 j).
//  - j-tile staged in LDS with sentinel +1e30 for non-neg; i sentinel -1e30 for
//    non-pos -> branch-free fmaxf(pi - pj, 0).
//  - jb==0 blocks also compute the trivial term + pos/neg counts for their i's.
//  - last-finished block (device-scope ticket) reads the atomically-accumulated
//    sums with agent-scope atomic loads and writes out[0].

#define NT  256   // threads per block
#define IPT 2     // i's per thread
#define IPB (NT * IPT)
#define JT  256   // j-tile size (LDS)

__global__ void __launch_bounds__(NT)
fused_kernel(const float* __restrict__ pred, const int* __restrict__ target,
             float* __restrict__ ws, float* __restrict__ out,
             int n, int nblocks) {
    __shared__ float s_pj[JT];
    __shared__ float s_red[NT / 64];
    __shared__ float s_tr[NT / 64];
    __shared__ int   s_pos[NT / 64], s_neg[NT / 64];

    int tid = threadIdx.x;
    int ib = blockIdx.x, jb = blockIdx.y;
    bool do_stats = (jb == 0);

    // stage j-tile (neg candidates); sentinel +1e30 contributes 0
    int j = jb * JT + tid;
    float pj = 1e30f;
    if (j < n && target[j] == 0) pj = pred[j];
    s_pj[tid] = pj;

    // own i's (pos candidates); sentinel -1e30 contributes 0
    float pi[IPT];
    float trivial = 0.0f;
    int pos = 0, neg = 0;
    #pragma unroll
    for (int t = 0; t < IPT; ++t) {
        int i = ib * IPB + t * NT + tid;
        float p = 0.0f;
        int tg = -1;
        if (i < n) { p = pred[i]; tg = target[i]; }
        pi[t] = (tg == 1) ? p : -1e30f;
        if (do_stats && i < n) {
            trivial += 1.0f / (p * p + 1e-5f);
            pos += (tg == 1);
            neg += (tg == 0);
        }
    }
    __syncthreads();

    // inner product of tiles: one broadcast ds_read_b128 feeds IPT*4 pairs
    float4 acc[IPT];
    #pragma unroll
    for (int t = 0; t < IPT; ++t) acc[t] = make_float4(0.f, 0.f, 0.f, 0.f);
    const float4* s4 = (const float4*)s_pj;
    #pragma unroll 8
    for (int k = 0; k < JT / 4; ++k) {
        float4 v = s4[k];
        #pragma unroll
        for (int t = 0; t < IPT; ++t) {
            acc[t].x += fmaxf(pi[t] - v.x, 0.0f);
            acc[t].y += fmaxf(pi[t] - v.y, 0.0f);
            acc[t].z += fmaxf(pi[t] - v.z, 0.0f);
            acc[t].w += fmaxf(pi[t] - v.w, 0.0f);
        }
    }
    float a = 0.0f;
    #pragma unroll
    for (int t = 0; t < IPT; ++t)
        a += (acc[t].x + acc[t].y) + (acc[t].z + acc[t].w);

    // wave(64) reduction
    for (int off = 32; off > 0; off >>= 1) {
        a += __shfl_down(a, off, 64);
        if (do_stats) {
            trivial += __shfl_down(trivial, off, 64);
            pos     += __shfl_down(pos, off, 64);
            neg     += __shfl_down(neg, off, 64);
        }
    }
    int lane = tid & 63, wv = tid >> 6;
    if (lane == 0) {
        s_red[wv] = a;
        if (do_stats) { s_tr[wv] = trivial; s_pos[wv] = pos; s_neg[wv] = neg; }
    }
    __syncthreads();

    if (tid == 0) {
        float A = 0.f, T = 0.f;
        int P = 0, Ng = 0;
        #pragma unroll
        for (int w = 0; w < NT / 64; ++w) {
            A += s_red[w];
            if (do_stats) { T += s_tr[w]; P += s_pos[w]; Ng += s_neg[w]; }
        }
        atomicAdd(&ws[0], A);
        if (do_stats) {
            atomicAdd(&ws[1], T);
            atomicAdd((int*)ws + 2, P);
            atomicAdd((int*)ws + 3, Ng);
        }
        __threadfence();  // release our partials before taking a ticket
        int done = __hip_atomic_fetch_add((int*)ws + 4, 1,
                                          __ATOMIC_ACQ_REL, __HIP_MEMORY_SCOPE_AGENT);
        if (done == nblocks - 1) {
            float loss = __hip_atomic_load(&ws[0], __ATOMIC_RELAXED, __HIP_MEMORY_SCOPE_AGENT);
            float tr   = __hip_atomic_load(&ws[1], __ATOMIC_RELAXED, __HIP_MEMORY_SCOPE_AGENT);
            int   P2   = __hip_atomic_load((int*)ws + 2, __ATOMIC_RELAXED, __HIP_MEMORY_SCOPE_AGENT);
            int   N2   = __hip_atomic_load((int*)ws + 3, __ATOMIC_RELAXED, __HIP_MEMORY_SCOPE_AGENT);
            float N = (float)P2 * (float)N2;
            out[0] = tr / (float)n + loss / N;
        }
    }
}

extern "C" void kernel_launch(void* const* d_in, const int* in_sizes, int n_in,
                              void* d_out, int out_size, void* d_ws, size_t ws_size,
                              hipStream_t stream) {
    const float* pred   = (const float*)d_in[0];
    const int*   target = (const int*)d_in[1];
    int n = in_sizes[0];
    float* ws = (float*)d_ws;

    hipMemsetAsync(d_ws, 0, 32, stream);

    int gx = (n + IPB - 1) / IPB;  // 16 at n=8192
    int gy = (n + JT - 1) / JT;    // 32 at n=8192
    dim3 grid(gx, gy);             // 512 blocks
    fused_kernel<<<grid, NT, 0, stream>>>(pred, target, ws, (float*)d_out,
                                          n, gx * gy);
}